// Round 15
// baseline (519.952 us; speedup 1.0000x reference)
//
#include <hip/hip_runtime.h>

typedef unsigned short u16;
typedef unsigned int u32;
typedef __attribute__((ext_vector_type(8))) short bf16x8;
typedef __attribute__((ext_vector_type(4))) float f32x4;
typedef __attribute__((ext_vector_type(4))) int i32x4;
typedef __attribute__((ext_vector_type(2))) unsigned int u32x2;

// T=4096 tokens, D=1024, F=4096, E=8, K=2. Inputs fp32.
// ws: xb(8M) | H(64M) | w1t(64M) | w3t(64M) | w2t(64M) | wa/alist/cnt

__device__ __forceinline__ u16 f2bf(float f) {
  u32 u = __builtin_bit_cast(u32, f);
  u += 0x7fffu + ((u >> 16) & 1u);
  return (u16)(u >> 16);
}
__device__ __forceinline__ u32 pack2(u16 a, u16 b) { return (u32)a | ((u32)b << 16); }
__device__ __forceinline__ u32 cvt2(float a, float b) { return pack2(f2bf(a), f2bf(b)); }

// XOR-swizzled LDS byte address for [row][64 bf16] GEMM tiles (128B rows); 16B-unit swizzle.
__device__ __forceinline__ char* lds_swz(void* base, int row, int byteInRow) {
  return (char*)base + (((row << 7) + byteInRow) ^ ((row & 7) << 4));
}

// async global->LDS, 16B per lane; LDS dest = wave-uniform base + lane*16, global src per-lane.
#define GLL16(g, l) __builtin_amdgcn_global_load_lds( \
    (const __attribute__((address_space(1))) void*)(g), \
    (__attribute__((address_space(3))) void*)(l), 16, 0, 0)

// ---- 64x64 fp32->bf16 transpose tile helper (tid-parameterized, 256-thread logic) ----
__device__ __forceinline__ void wtrans_tile2(const float* __restrict__ src, u16* __restrict__ dst,
                                             int R, int C, int c0, int r0, void* lds, int tid)
{
  u16 (*t)[72] = (u16 (*)[72])lds;
  const int rr = (tid >> 4) * 4, cc = (tid & 15) * 4;
  f32x4 v[4];
#pragma unroll
  for (int j = 0; j < 4; ++j) v[j] = *(const f32x4*)(src + (size_t)(r0 + rr + j) * C + c0 + cc);
#pragma unroll
  for (int c = 0; c < 4; ++c) {
    u32x2 p;
    p[0] = pack2(f2bf(v[0][c]), f2bf(v[1][c]));
    p[1] = pack2(f2bf(v[2][c]), f2bf(v[3][c]));
    *(u32x2*)&t[cc + c][rr] = p;
  }
  __syncthreads();
  const int c = tid >> 2, rs = (tid & 3) * 16;
  i32x4 a0 = *(const i32x4*)&t[c][rs];
  i32x4 a1 = *(const i32x4*)&t[c][rs + 8];
  u16* dp = dst + (size_t)(c0 + c) * R + r0 + rs;
  *(i32x4*)dp = a0;
  *(i32x4*)(dp + 8) = a1;
}

// ---------------- launch A: router (blocks 0-127) + w1/w3 transpose (R13-proven) ----------------
__global__ __launch_bounds__(256) void rp_k(
    const float* __restrict__ x, const float* __restrict__ gw,
    float* __restrict__ probs, u16* __restrict__ xb,
    float* __restrict__ wa, int* __restrict__ alist, int* __restrict__ cnt,
    const float* __restrict__ w1, const float* __restrict__ w3,
    u16* __restrict__ w1t, u16* __restrict__ w3t)
{
  __shared__ __align__(16) char smem[9216];
  const int bid = blockIdx.x;
  const int tid = threadIdx.x;

  if (bid >= 128) {
    const int b2 = bid - 128;
    const int sel = b2 >> 13;
    const int t0 = b2 & 8191;
    const int e = t0 >> 10;
    const int rem = t0 & 1023;
    const int xt = rem & 63, yt = rem >> 6;
    const float* src = (sel ? w3 : w1) + (size_t)e * 4194304;
    u16* dst = (sel ? w3t : w1t) + (size_t)e * 4194304;
    wtrans_tile2(src, dst, 1024, 4096, xt * 64, yt * 64, smem, tid);
    return;
  }

  int* lcnt  = (int*)smem;
  int* gbase = lcnt + 8;
  int* s_e   = gbase + 8;
  int* s_pos = s_e + 64;
  int* s_row = s_pos + 64;

  const int wv = tid >> 6, l = tid & 63;
  const int tb = bid * 32;

  if (tid < 8) lcnt[tid] = 0;
  __syncthreads();

  for (int i = 0; i < 8; ++i) {
    const int t = tb + wv * 8 + i;
    const float* xrow = x + (size_t)t * 1024;
    f32x4 xv[4];
#pragma unroll
    for (int j = 0; j < 4; ++j) xv[j] = *(const f32x4*)(xrow + j * 256 + l * 4);

    u16* xbt = xb + (size_t)t * 1024;
#pragma unroll
    for (int j = 0; j < 4; ++j) {
      u32x2 hb;
      hb[0] = cvt2(xv[j][0], xv[j][1]);
      hb[1] = cvt2(xv[j][2], xv[j][3]);
      *(u32x2*)(xbt + j * 256 + l * 4) = hb;
    }

    float acc[8];
#pragma unroll
    for (int e = 0; e < 8; ++e) acc[e] = 0.f;
#pragma unroll
    for (int j = 0; j < 4; ++j) {
      const float* g = gw + j * 2048 + l * 32;
#pragma unroll
      for (int c = 0; c < 4; ++c)
#pragma unroll
        for (int e = 0; e < 8; ++e) acc[e] = fmaf(xv[j][c], g[c * 8 + e], acc[e]);
    }
#pragma unroll
    for (int e = 0; e < 8; ++e)
      for (int off = 32; off > 0; off >>= 1) acc[e] += __shfl_down(acc[e], off);

    if (l == 0) {
      float p[8]; float mx = -1e30f;
#pragma unroll
      for (int e = 0; e < 8; ++e) { p[e] = acc[e]; mx = fmaxf(mx, p[e]); }
      float s = 0.f;
#pragma unroll
      for (int e = 0; e < 8; ++e) { p[e] = __expf(p[e] - mx); s += p[e]; }
      float inv = 1.f / s;
#pragma unroll
      for (int e = 0; e < 8; ++e) { p[e] *= inv; probs[(size_t)t * 8 + e] = p[e]; }
      int i0 = 0;
#pragma unroll
      for (int e = 1; e < 8; ++e) if (p[e] > p[i0]) i0 = e;
      int i1 = (i0 == 0) ? 1 : 0;
#pragma unroll
      for (int e = 0; e < 8; ++e) if (e != i0 && p[e] > p[i1]) i1 = e;
      float s2 = p[i0] + p[i1];
      int p0 = atomicAdd(&lcnt[i0], 1);
      int p1 = atomicAdd(&lcnt[i1], 1);
      const int si = (wv * 8 + i) * 2;
      s_e[si] = i0;   s_pos[si] = p0;   s_row[si] = t * 2;
      s_e[si+1] = i1; s_pos[si+1] = p1; s_row[si+1] = t * 2 + 1;
      wa[t * 2]     = p[i0] / s2;
      wa[t * 2 + 1] = p[i1] / s2;
    }
  }
  __syncthreads();
  if (tid < 8) gbase[tid] = atomicAdd(&cnt[tid], lcnt[tid]);
  __syncthreads();
  if (tid < 64) {
    int e = s_e[tid];
    alist[e * 4096 + gbase[e] + s_pos[tid]] = s_row[tid];
  }
}

// ---------------- gemm1: 256x256 8-wave 8-phase (T3+T4+T5), + w2-prep overlay ----------------
// bx<32: gemm1; bx 32-39: w2 prep (8 tiles/block, two 256-thread halves).
// B-tile interleave: slot g (0-15): mat=(g>>2)&1, fgroup=(g&3)+((g>>3)<<2) -> wave wc holds
// (c1,c3) pairs at same f. Wave frag ownership interleaved: m-frag = mi*2+wr, n-slot = ni*4+wc,
// so phase quadrant (MH,NH) consumes exactly A-half MH / B-half NH.
__global__ __launch_bounds__(512, 2) void gemm1p_k(
    const u16* __restrict__ xb, const u16* __restrict__ w1t, const u16* __restrict__ w3t,
    const int* __restrict__ alist, const int* __restrict__ cnt, u16* __restrict__ H,
    const float* __restrict__ w2, u16* __restrict__ w2t)
{
  __shared__ u16 As[2][256][64];   // 64 KB
  __shared__ u16 Bs[2][256][64];   // 64 KB
  __shared__ int rowid[256];

  const int e = blockIdx.z;
  const int bx = blockIdx.x;
  const int tid = threadIdx.x;

  if (bx >= 32) {
    // ---- w2 prep overlay: [4096f][1024d] fp32 -> [1024d][4096f] bf16
    const int half = tid >> 8, t2 = tid & 255;
    char* psm = (char*)&As[0][0][0] + half * 9216;
    const int slot = (bx - 32) * 128 + blockIdx.y * 8 + e;   // 0..1023
#pragma unroll
    for (int j = 0; j < 4; ++j) {
      const int tj = slot * 8 + j * 2 + half;                // 0..8191
      const int e2 = tj >> 10, idx = tj & 1023;
      const float* src = w2 + (size_t)e2 * 4194304;
      u16* dst = w2t + (size_t)e2 * 4194304;
      wtrans_tile2(src, dst, 4096, 1024, (idx & 15) * 64, (idx >> 4) * 64, psm, t2);
      __syncthreads();
    }
    return;
  }

  const int mc = cnt[e];
  const int m0 = blockIdx.y * 256;
  if (m0 >= mc) return;
  const int f0 = bx * 128;

  if (tid < 256) rowid[tid] = (m0 + tid < mc) ? alist[e * 4096 + m0 + tid] : -1;
  __syncthreads();

  const int w = tid >> 6, l = tid & 63;
  const int wr = w >> 2, wc = w & 3;             // 2M x 4N wave grid
  const int l15 = l & 15, lg = l >> 4;

  // staging pointers: [half][q], row = half*128 + w*8 + (l>>3) + q*64
  const u16* aptr[2][2]; const u16* bptr[2][2];
#pragma unroll
  for (int hh = 0; hh < 2; ++hh)
#pragma unroll
    for (int q = 0; q < 2; ++q) {
      const int r = hh * 128 + w * 8 + (l >> 3) + q * 64;
      const int id = rowid[r];
      aptr[hh][q] = xb + (size_t)(id < 0 ? 0 : (id >> 1)) * 1024 + ((l & 7) ^ (r & 7)) * 8;
      const int g = r >> 4, sub = r & 15;
      const int mat = (g >> 2) & 1;
      const int fg = (g & 3) + ((g >> 3) << 2);
      const int f = f0 + fg * 16 + sub;
      bptr[hh][q] = (mat ? w3t : w1t) + (size_t)e * 4194304 + (size_t)f * 1024 + ((l & 7) ^ (r & 7)) * 8;
    }

#define STAGE_A(B_, H_, KT) do { \
    GLL16(aptr[H_][0] + (KT) * 64, &As[B_][(H_) * 128 + w * 8][0]); \
    GLL16(aptr[H_][1] + (KT) * 64, &As[B_][(H_) * 128 + w * 8 + 64][0]); \
  } while (0)
#define STAGE_B(B_, H_, KT) do { \
    GLL16(bptr[H_][0] + (KT) * 64, &Bs[B_][(H_) * 128 + w * 8][0]); \
    GLL16(bptr[H_][1] + (KT) * 64, &Bs[B_][(H_) * 128 + w * 8 + 64][0]); \
  } while (0)

  f32x4 acc[8][4];
  const f32x4 zf = {0.f, 0.f, 0.f, 0.f};
#pragma unroll
  for (int mi = 0; mi < 8; ++mi)
#pragma unroll
    for (int ni = 0; ni < 4; ++ni) acc[mi][ni] = zf;

#define PHASE(MH, NH, STG) do { \
    void* Ab = (void*)((char*)&As[0][0][0] + b * 32768); \
    void* Bb = (void*)((char*)&Bs[0][0][0] + b * 32768); \
    bf16x8 af[4][2], bfr[2][2]; \
    _Pragma("unroll") \
    for (int ks = 0; ks < 2; ++ks) { \
      _Pragma("unroll") \
      for (int i = 0; i < 4; ++i) \
        af[i][ks] = *(const bf16x8*)lds_swz(Ab, (((MH) * 4 + i) * 2 + wr) * 16 + l15, ks * 64 + lg * 16); \
      _Pragma("unroll") \
      for (int j = 0; j < 2; ++j) \
        bfr[j][ks] = *(const bf16x8*)lds_swz(Bb, (((NH) * 2 + j) * 4 + wc) * 16 + l15, ks * 64 + lg * 16); \
    } \
    STG; \
    __builtin_amdgcn_s_barrier(); \
    __builtin_amdgcn_s_setprio(1); \
    _Pragma("unroll") \
    for (int ks = 0; ks < 2; ++ks) \
      _Pragma("unroll") \
      for (int i = 0; i < 4; ++i) \
        _Pragma("unroll") \
        for (int j = 0; j < 2; ++j) \
          acc[(MH) * 4 + i][(NH) * 2 + j] = __builtin_amdgcn_mfma_f32_16x16x32_bf16( \
              af[i][ks], bfr[j][ks], acc[(MH) * 4 + i][(NH) * 2 + j], 0, 0, 0); \
    __builtin_amdgcn_s_setprio(0); \
  } while (0)

  // ---- prologue: tile0 all 4 halves + tile1 lo halves (6 stages, 12 vm); keep 2 in flight
  STAGE_A(0, 0, 0); STAGE_B(0, 0, 0); STAGE_A(0, 1, 0); STAGE_B(0, 1, 0);
  STAGE_A(1, 0, 1); STAGE_B(1, 0, 1);
  asm volatile("s_waitcnt vmcnt(4)" ::: "memory");
  __builtin_amdgcn_s_barrier();

  for (int t = 0; t < 16; ++t) {
    const int b = t & 1;
    PHASE(0, 0, if (t + 1 < 16) STAGE_A(b ^ 1, 1, t + 1));
    __builtin_amdgcn_s_barrier();
    PHASE(0, 1, if (t + 1 < 16) STAGE_B(b ^ 1, 1, t + 1));
    __builtin_amdgcn_s_barrier();
    PHASE(1, 0, if (t + 2 < 16) STAGE_A(b, 0, t + 2));
    __builtin_amdgcn_s_barrier();
    PHASE(1, 1, if (t + 2 < 16) STAGE_B(b, 0, t + 2));
    if (t <= 13) asm volatile("s_waitcnt vmcnt(4)" ::: "memory");
    else         asm volatile("s_waitcnt vmcnt(0)" ::: "memory");
    __builtin_amdgcn_s_barrier();
  }

  // ---- epilogue: pairs (ni=2p, ni=2p+1) = (c1, c3) at f = f0 + (wc + p*4)*16 + l15
#pragma unroll
  for (int mi = 0; mi < 8; ++mi) {
    const int rbase = (mi * 2 + wr) * 16 + lg * 4;
#pragma unroll
    for (int pr = 0; pr < 2; ++pr) {
      const int f = f0 + (wc + pr * 4) * 16 + l15;
      f32x4 c1 = acc[mi][pr * 2], c3 = acc[mi][pr * 2 + 1];
#pragma unroll
      for (int j = 0; j < 4; ++j) {
        int id = rowid[rbase + j];
        if (id >= 0) {
          float a = c1[j];
          H[(size_t)id * 4096 + f] = f2bf((a / (1.f + __expf(-a))) * c3[j]);
        }
      }
    }
  }
#undef PHASE
#undef STAGE_A
#undef STAGE_B
}

// ---------------- gemm2: out[token] += wa * (H @ w2), split-K=4, fused combine (R13-proven) ----------------
__global__ __launch_bounds__(256, 2) void gemm2_k(
    const u16* __restrict__ H, const u16* __restrict__ w2t,
    const int* __restrict__ alist, const int* __restrict__ cnt,
    const float* __restrict__ wa, float* __restrict__ out)
{
  const int e = blockIdx.z;
  const int mc = cnt[e];
  const int yy = blockIdx.y;
  const int kq = yy & 3;
  const int m0 = (yy >> 2) * 128;
  if (m0 >= mc) return;
  const int n0 = blockIdx.x * 128;
  const int tid = threadIdx.x;

  __shared__ u16 As[128 * 64];
  __shared__ u16 Bs[128 * 64];
  __shared__ int rowid[128];
  __shared__ float rw[128];

  if (tid < 128) {
    int id = (m0 + tid < mc) ? alist[e * 4096 + m0 + tid] : -1;
    rowid[tid] = id;
    rw[tid] = (id >= 0) ? wa[id] : 0.f;
  }
  __syncthreads();

  const int l = tid & 63, w = tid >> 6;
  const size_t kbase = (size_t)kq * 1024;
  const u16* aps[4]; const u16* bps[4];
  u16* ald[4]; u16* bld[4];
#pragma unroll
  for (int q = 0; q < 4; ++q) {
    int ra = 32 * w + 8 * q + (l >> 3);
    int id = rowid[ra];
    aps[q] = H + (size_t)(id < 0 ? 0 : id) * 4096 + kbase + ((l & 7) ^ (ra & 7)) * 8;
    ald[q] = As + (32 * w + 8 * q) * 64;
    int rb = 32 * w + 8 * q + (l >> 3);
    bps[q] = w2t + (size_t)e * 4194304 + (size_t)(n0 + rb) * 4096 + kbase + ((l & 7) ^ (rb & 7)) * 8;
    bld[q] = Bs + (32 * w + 8 * q) * 64;
  }

  const int wm = (w >> 1) * 64, wn = (w & 1) * 64;
  const int l15 = l & 15, lg = l >> 4;

  f32x4 acc[4][4];
  const f32x4 zf = {0.f, 0.f, 0.f, 0.f};
#pragma unroll
  for (int mi = 0; mi < 4; ++mi)
#pragma unroll
    for (int ni = 0; ni < 4; ++ni) acc[mi][ni] = zf;

  for (int kt = 0; kt < 16; ++kt) {
    const int ko = kt * 64;
#pragma unroll
    for (int q = 0; q < 4; ++q) GLL16(aps[q] + ko, ald[q]);
#pragma unroll
    for (int q = 0; q < 4; ++q) GLL16(bps[q] + ko, bld[q]);
    __syncthreads();
#pragma unroll
    for (int ks = 0; ks < 2; ++ks) {
      const int kb = ks * 64 + lg * 16;
      bf16x8 af[4];
#pragma unroll
      for (int mi = 0; mi < 4; ++mi)
        af[mi] = *(const bf16x8*)lds_swz(As, wm + mi * 16 + l15, kb);
#pragma unroll
      for (int ni = 0; ni < 4; ++ni) {
        bf16x8 bfb = *(const bf16x8*)lds_swz(Bs, wn + ni * 16 + l15, kb);
#pragma unroll
        for (int mi = 0; mi < 4; ++mi)
          acc[mi][ni] = __builtin_amdgcn_mfma_f32_16x16x32_bf16(af[mi], bfb, acc[mi][ni], 0, 0, 0);
      }
    }
    __syncthreads();
  }

#pragma unroll
  for (int mi = 0; mi < 4; ++mi) {
    const int rb = wm + mi * 16 + lg * 4;
#pragma unroll
    for (int ni = 0; ni < 4; ++ni) {
      const int col = n0 + wn + ni * 16 + l15;
      f32x4 c = acc[mi][ni];
#pragma unroll
      for (int j = 0; j < 4; ++j) {
        int rr = rb + j;
        int id = rowid[rr];
        if (id >= 0)
          unsafeAtomicAdd(&out[(size_t)(id >> 1) * 1024 + col], c[j] * rw[rr]);
      }
    }
  }
}

extern "C" void kernel_launch(void* const* d_in, const int* in_sizes, int n_in,
                              void* d_out, int out_size, void* d_ws, size_t ws_size,
                              hipStream_t stream)
{
  (void)in_sizes; (void)n_in; (void)out_size; (void)ws_size;
  const float* x  = (const float*)d_in[0];
  const float* gw = (const float*)d_in[1];
  const float* w1 = (const float*)d_in[2];
  const float* w3 = (const float*)d_in[3];
  const float* w2 = (const float*)d_in[4];
  float* out   = (float*)d_out;
  float* probs = out + (size_t)4096 * 1024;

  const size_t MB = (size_t)1 << 20;
  char* ws = (char*)d_ws;
  u16*   xb    = (u16*)(ws);
  u16*   H     = (u16*)(ws + 8 * MB);
  u16*   w1t   = (u16*)(ws + 72 * MB);
  u16*   w3t   = (u16*)(ws + 136 * MB);
  u16*   w2t   = (u16*)(ws + 200 * MB);
  float* wa    = (float*)(ws + 264 * MB);
  int*   alist = (int*)(ws + 264 * MB + 32768);
  int*   cnt   = (int*)(ws + 264 * MB + 32768 + 131072);

  (void)hipMemsetAsync(cnt, 0, 8 * sizeof(int), stream);
  (void)hipMemsetAsync(out, 0, (size_t)4096 * 1024 * sizeof(float), stream);
  rp_k<<<16512, 256, 0, stream>>>(x, gw, probs, xb, wa, alist, cnt, w1, w3, w1t, w3t);
  gemm1p_k<<<dim3(40, 16, 8), 512, 0, stream>>>(xb, w1t, w3t, alist, cnt, H, w2, w2t);
  gemm2_k<<<dim3(8, 128, 8), 256, 0, stream>>>(H, w2t, alist, cnt, wa, out);
}

// Round 16
// 489.308 us; speedup vs baseline: 1.0626x; 1.0626x over previous
//
#include <hip/hip_runtime.h>

typedef unsigned short u16;
typedef unsigned int u32;
typedef __attribute__((ext_vector_type(8))) short bf16x8;
typedef __attribute__((ext_vector_type(4))) float f32x4;
typedef __attribute__((ext_vector_type(4))) int i32x4;
typedef __attribute__((ext_vector_type(2))) unsigned int u32x2;

// T=4096 tokens, D=1024, F=4096, E=8, K=2. Inputs fp32.
// ws: xb(8M) | H(64M) | w1t(64M) | w3t(64M) | w2t(64M) | wa/alist/cnt

__device__ __forceinline__ u16 f2bf(float f) {
  u32 u = __builtin_bit_cast(u32, f);
  u += 0x7fffu + ((u >> 16) & 1u);
  return (u16)(u >> 16);
}
__device__ __forceinline__ u32 pack2(u16 a, u16 b) { return (u32)a | ((u32)b << 16); }
__device__ __forceinline__ u32 cvt2(float a, float b) { return pack2(f2bf(a), f2bf(b)); }

__device__ __forceinline__ char* lds_swz(void* base, int row, int byteInRow) {
  return (char*)base + (((row << 7) + byteInRow) ^ ((row & 7) << 4));
}

#define GLL16(g, l) __builtin_amdgcn_global_load_lds( \
    (const __attribute__((address_space(1))) void*)(g), \
    (__attribute__((address_space(3))) void*)(l), 16, 0, 0)

// ---- 64x64 fp32->bf16 transpose tile helper ----
__device__ __forceinline__ void wtrans_tile2(const float* __restrict__ src, u16* __restrict__ dst,
                                             int R, int C, int c0, int r0, void* lds, int tid)
{
  u16 (*t)[72] = (u16 (*)[72])lds;
  const int rr = (tid >> 4) * 4, cc = (tid & 15) * 4;
  f32x4 v[4];
#pragma unroll
  for (int j = 0; j < 4; ++j) v[j] = *(const f32x4*)(src + (size_t)(r0 + rr + j) * C + c0 + cc);
#pragma unroll
  for (int c = 0; c < 4; ++c) {
    u32x2 p;
    p[0] = pack2(f2bf(v[0][c]), f2bf(v[1][c]));
    p[1] = pack2(f2bf(v[2][c]), f2bf(v[3][c]));
    *(u32x2*)&t[cc + c][rr] = p;
  }
  __syncthreads();
  const int c = tid >> 2, rs = (tid & 3) * 16;
  i32x4 a0 = *(const i32x4*)&t[c][rs];
  i32x4 a1 = *(const i32x4*)&t[c][rs + 8];
  u16* dp = dst + (size_t)(c0 + c) * R + r0 + rs;
  *(i32x4*)dp = a0;
  *(i32x4*)(dp + 8) = a1;
}

// ---------------- launch A: router + w1/w3 + w2 transpose ----------------
__global__ __launch_bounds__(256) void rp_k(
    const float* __restrict__ x, const float* __restrict__ gw,
    float* __restrict__ probs, u16* __restrict__ xb,
    float* __restrict__ wa, int* __restrict__ alist, int* __restrict__ cnt,
    const float* __restrict__ w1, const float* __restrict__ w3,
    u16* __restrict__ w1t, u16* __restrict__ w3t,
    const float* __restrict__ w2, u16* __restrict__ w2t)
{
  __shared__ __align__(16) char smem[9216];
  const int bid = blockIdx.x;
  const int tid = threadIdx.x;

  if (bid >= 16512) {
    // ---- w2 prep: 4 tiles per block
    const int slot = bid - 16512;            // 0..2047
#pragma unroll
    for (int j = 0; j < 4; ++j) {
      const int tj = slot * 4 + j;           // 0..8191
      const int e2 = tj >> 10, idx = tj & 1023;
      const float* src = w2 + (size_t)e2 * 4194304;
      u16* dst = w2t + (size_t)e2 * 4194304;
      wtrans_tile2(src, dst, 4096, 1024, (idx & 15) * 64, (idx >> 4) * 64, smem, tid);
      __syncthreads();
    }
    return;
  }
  if (bid >= 128) {
    const int b2 = bid - 128;
    const int sel = b2 >> 13;
    const int t0 = b2 & 8191;
    const int e = t0 >> 10;
    const int rem = t0 & 1023;
    const int xt = rem & 63, yt = rem >> 6;
    const float* src = (sel ? w3 : w1) + (size_t)e * 4194304;
    u16* dst = (sel ? w3t : w1t) + (size_t)e * 4194304;
    wtrans_tile2(src, dst, 1024, 4096, xt * 64, yt * 64, smem, tid);
    return;
  }

  int* lcnt  = (int*)smem;
  int* gbase = lcnt + 8;
  int* s_e   = gbase + 8;
  int* s_pos = s_e + 64;
  int* s_row = s_pos + 64;

  const int wv = tid >> 6, l = tid & 63;
  const int tb = bid * 32;

  if (tid < 8) lcnt[tid] = 0;
  __syncthreads();

  for (int i = 0; i < 8; ++i) {
    const int t = tb + wv * 8 + i;
    const float* xrow = x + (size_t)t * 1024;
    f32x4 xv[4];
#pragma unroll
    for (int j = 0; j < 4; ++j) xv[j] = *(const f32x4*)(xrow + j * 256 + l * 4);

    u16* xbt = xb + (size_t)t * 1024;
#pragma unroll
    for (int j = 0; j < 4; ++j) {
      u32x2 hb;
      hb[0] = cvt2(xv[j][0], xv[j][1]);
      hb[1] = cvt2(xv[j][2], xv[j][3]);
      *(u32x2*)(xbt + j * 256 + l * 4) = hb;
    }

    float acc[8];
#pragma unroll
    for (int e = 0; e < 8; ++e) acc[e] = 0.f;
#pragma unroll
    for (int j = 0; j < 4; ++j) {
      const float* g = gw + j * 2048 + l * 32;
#pragma unroll
      for (int c = 0; c < 4; ++c)
#pragma unroll
        for (int e = 0; e < 8; ++e) acc[e] = fmaf(xv[j][c], g[c * 8 + e], acc[e]);
    }
#pragma unroll
    for (int e = 0; e < 8; ++e)
      for (int off = 32; off > 0; off >>= 1) acc[e] += __shfl_down(acc[e], off);

    if (l == 0) {
      float p[8]; float mx = -1e30f;
#pragma unroll
      for (int e = 0; e < 8; ++e) { p[e] = acc[e]; mx = fmaxf(mx, p[e]); }
      float s = 0.f;
#pragma unroll
      for (int e = 0; e < 8; ++e) { p[e] = __expf(p[e] - mx); s += p[e]; }
      float inv = 1.f / s;
#pragma unroll
      for (int e = 0; e < 8; ++e) { p[e] *= inv; probs[(size_t)t * 8 + e] = p[e]; }
      int i0 = 0;
#pragma unroll
      for (int e = 1; e < 8; ++e) if (p[e] > p[i0]) i0 = e;
      int i1 = (i0 == 0) ? 1 : 0;
#pragma unroll
      for (int e = 0; e < 8; ++e) if (e != i0 && p[e] > p[i1]) i1 = e;
      float s2 = p[i0] + p[i1];
      int p0 = atomicAdd(&lcnt[i0], 1);
      int p1 = atomicAdd(&lcnt[i1], 1);
      const int si = (wv * 8 + i) * 2;
      s_e[si] = i0;   s_pos[si] = p0;   s_row[si] = t * 2;
      s_e[si+1] = i1; s_pos[si+1] = p1; s_row[si+1] = t * 2 + 1;
      wa[t * 2]     = p[i0] / s2;
      wa[t * 2 + 1] = p[i1] / s2;
    }
  }
  __syncthreads();
  if (tid < 8) gbase[tid] = atomicAdd(&cnt[tid], lcnt[tid]);
  __syncthreads();
  if (tid < 64) {
    int e = s_e[tid];
    alist[e * 4096 + gbase[e] + s_pos[tid]] = s_row[tid];
  }
}

// ---------------- gemm1: 256x256 8-wave 4-phase snake with operand reuse ----------------
// Phases: (0,0)->(0,1)->(1,1)->(1,0). af reloaded on MH change; b0/b1 held whole tile.
// Reads/K-tile/wave: 12+4+8+0 = 24 ds_read_b128 (minimal).
__global__ __launch_bounds__(512, 2) void gemm1p_k(
    const u16* __restrict__ xb, const u16* __restrict__ w1t, const u16* __restrict__ w3t,
    const int* __restrict__ alist, const int* __restrict__ cnt, u16* __restrict__ H)
{
  __shared__ u16 As[2][256][64];   // 64 KB
  __shared__ u16 Bs[2][256][64];   // 64 KB
  __shared__ int rowid[256];

  const int e = blockIdx.z;
  const int tid = threadIdx.x;
  const int mc = cnt[e];
  const int m0 = blockIdx.y * 256;
  if (m0 >= mc) return;
  const int f0 = blockIdx.x * 128;

  if (tid < 256) rowid[tid] = (m0 + tid < mc) ? alist[e * 4096 + m0 + tid] : -1;
  __syncthreads();

  const int w = tid >> 6, l = tid & 63;
  const int wr = w >> 2, wc = w & 3;             // 2M x 4N wave grid
  const int l15 = l & 15, lg = l >> 4;

  const u16* aptr[2][2]; const u16* bptr[2][2];
#pragma unroll
  for (int hh = 0; hh < 2; ++hh)
#pragma unroll
    for (int q = 0; q < 2; ++q) {
      const int r = hh * 128 + w * 8 + (l >> 3) + q * 64;
      const int id = rowid[r];
      aptr[hh][q] = xb + (size_t)(id < 0 ? 0 : (id >> 1)) * 1024 + ((l & 7) ^ (r & 7)) * 8;
      const int g = r >> 4, sub = r & 15;
      const int mat = (g >> 2) & 1;
      const int fg = (g & 3) + ((g >> 3) << 2);
      const int f = f0 + fg * 16 + sub;
      bptr[hh][q] = (mat ? w3t : w1t) + (size_t)e * 4194304 + (size_t)f * 1024 + ((l & 7) ^ (r & 7)) * 8;
    }

#define STAGE_A(B_, H_, KT) do { \
    GLL16(aptr[H_][0] + (KT) * 64, &As[B_][(H_) * 128 + w * 8][0]); \
    GLL16(aptr[H_][1] + (KT) * 64, &As[B_][(H_) * 128 + w * 8 + 64][0]); \
  } while (0)
#define STAGE_B(B_, H_, KT) do { \
    GLL16(bptr[H_][0] + (KT) * 64, &Bs[B_][(H_) * 128 + w * 8][0]); \
    GLL16(bptr[H_][1] + (KT) * 64, &Bs[B_][(H_) * 128 + w * 8 + 64][0]); \
  } while (0)

  f32x4 acc[8][4];
  const f32x4 zf = {0.f, 0.f, 0.f, 0.f};
#pragma unroll
  for (int mi = 0; mi < 8; ++mi)
#pragma unroll
    for (int ni = 0; ni < 4; ++ni) acc[mi][ni] = zf;

  bf16x8 af[4][2], b0[2][2], b1[2][2];

#define LOAD_A(MH) do { \
    _Pragma("unroll") \
    for (int ks = 0; ks < 2; ++ks) \
      _Pragma("unroll") \
      for (int i = 0; i < 4; ++i) \
        af[i][ks] = *(const bf16x8*)lds_swz(Ab, (((MH) * 4 + i) * 2 + wr) * 16 + l15, ks * 64 + lg * 16); \
  } while (0)
#define LOAD_B(DST, NH) do { \
    _Pragma("unroll") \
    for (int ks = 0; ks < 2; ++ks) \
      _Pragma("unroll") \
      for (int j = 0; j < 2; ++j) \
        DST[j][ks] = *(const bf16x8*)lds_swz(Bb, (((NH) * 2 + j) * 4 + wc) * 16 + l15, ks * 64 + lg * 16); \
  } while (0)
#define MFMA_Q(MH, NH, BF) do { \
    __builtin_amdgcn_s_barrier(); \
    __builtin_amdgcn_s_setprio(1); \
    _Pragma("unroll") \
    for (int ks = 0; ks < 2; ++ks) \
      _Pragma("unroll") \
      for (int i = 0; i < 4; ++i) \
        _Pragma("unroll") \
        for (int j = 0; j < 2; ++j) \
          acc[(MH) * 4 + i][(NH) * 2 + j] = __builtin_amdgcn_mfma_f32_16x16x32_bf16( \
              af[i][ks], BF[j][ks], acc[(MH) * 4 + i][(NH) * 2 + j], 0, 0, 0); \
    __builtin_amdgcn_s_setprio(0); \
  } while (0)

  // ---- prologue: tile0 full + tile1 lo halves (12 GLL); drain tile0 (keep 4 in flight)
  STAGE_A(0, 0, 0); STAGE_B(0, 0, 0); STAGE_A(0, 1, 0); STAGE_B(0, 1, 0);
  STAGE_A(1, 0, 1); STAGE_B(1, 0, 1);
  asm volatile("s_waitcnt vmcnt(4)" ::: "memory");
  __builtin_amdgcn_s_barrier();

  for (int t = 0; t < 16; ++t) {
    const int b = t & 1;
    void* Ab = (void*)((char*)&As[0][0][0] + b * 32768);
    void* Bb = (void*)((char*)&Bs[0][0][0] + b * 32768);
    // P1 (0,0): load af(MH0)+b0; stage A-hi(t+1)
    LOAD_A(0); LOAD_B(b0, 0);
    if (t + 1 < 16) STAGE_A(b ^ 1, 1, t + 1);
    MFMA_Q(0, 0, b0);
    __builtin_amdgcn_s_barrier();
    // P2 (0,1): load b1; stage B-hi(t+1)
    LOAD_B(b1, 1);
    if (t + 1 < 16) STAGE_B(b ^ 1, 1, t + 1);
    MFMA_Q(0, 1, b1);
    __builtin_amdgcn_s_barrier();
    // P3 (1,1): load af(MH1); stage A-lo(t+2)
    LOAD_A(1);
    if (t + 2 < 16) STAGE_A(b, 0, t + 2);
    MFMA_Q(1, 1, b1);
    __builtin_amdgcn_s_barrier();
    // P4 (1,0): no loads; stage B-lo(t+2)
    if (t + 2 < 16) STAGE_B(b, 0, t + 2);
    MFMA_Q(1, 0, b0);
    if (t <= 13) asm volatile("s_waitcnt vmcnt(4)" ::: "memory");
    else         asm volatile("s_waitcnt vmcnt(0)" ::: "memory");
    __builtin_amdgcn_s_barrier();
  }

  // ---- epilogue: (c1,c3) pairs at f = f0 + (wc + pr*4)*16 + l15
#pragma unroll
  for (int mi = 0; mi < 8; ++mi) {
    const int rbase = (mi * 2 + wr) * 16 + lg * 4;
#pragma unroll
    for (int pr = 0; pr < 2; ++pr) {
      const int f = f0 + (wc + pr * 4) * 16 + l15;
      f32x4 c1 = acc[mi][pr * 2], c3 = acc[mi][pr * 2 + 1];
#pragma unroll
      for (int j = 0; j < 4; ++j) {
        int id = rowid[rbase + j];
        if (id >= 0) {
          float a = c1[j];
          H[(size_t)id * 4096 + f] = f2bf((a / (1.f + __expf(-a))) * c3[j]);
        }
      }
    }
  }
#undef MFMA_Q
#undef LOAD_A
#undef LOAD_B
#undef STAGE_A
#undef STAGE_B
}

// ---------------- gemm2: out[token] += wa * (H @ w2), split-K=4, fused combine ----------------
__global__ __launch_bounds__(256, 2) void gemm2_k(
    const u16* __restrict__ H, const u16* __restrict__ w2t,
    const int* __restrict__ alist, const int* __restrict__ cnt,
    const float* __restrict__ wa, float* __restrict__ out)
{
  const int e = blockIdx.z;
  const int mc = cnt[e];
  const int yy = blockIdx.y;
  const int kq = yy & 3;
  const int m0 = (yy >> 2) * 128;
  if (m0 >= mc) return;
  const int n0 = blockIdx.x * 128;
  const int tid = threadIdx.x;

  __shared__ u16 As[128 * 64];
  __shared__ u16 Bs[128 * 64];
  __shared__ int rowid[128];
  __shared__ float rw[128];

  if (tid < 128) {
    int id = (m0 + tid < mc) ? alist[e * 4096 + m0 + tid] : -1;
    rowid[tid] = id;
    rw[tid] = (id >= 0) ? wa[id] : 0.f;
  }
  __syncthreads();

  const int l = tid & 63, w = tid >> 6;
  const size_t kbase = (size_t)kq * 1024;
  const u16* aps[4]; const u16* bps[4];
  u16* ald[4]; u16* bld[4];
#pragma unroll
  for (int q = 0; q < 4; ++q) {
    int ra = 32 * w + 8 * q + (l >> 3);
    int id = rowid[ra];
    aps[q] = H + (size_t)(id < 0 ? 0 : id) * 4096 + kbase + ((l & 7) ^ (ra & 7)) * 8;
    ald[q] = As + (32 * w + 8 * q) * 64;
    int rb = 32 * w + 8 * q + (l >> 3);
    bps[q] = w2t + (size_t)e * 4194304 + (size_t)(n0 + rb) * 4096 + kbase + ((l & 7) ^ (rb & 7)) * 8;
    bld[q] = Bs + (32 * w + 8 * q) * 64;
  }

  const int wm = (w >> 1) * 64, wn = (w & 1) * 64;
  const int l15 = l & 15, lg = l >> 4;

  f32x4 acc[4][4];
  const f32x4 zf = {0.f, 0.f, 0.f, 0.f};
#pragma unroll
  for (int mi = 0; mi < 4; ++mi)
#pragma unroll
    for (int ni = 0; ni < 4; ++ni) acc[mi][ni] = zf;

  for (int kt = 0; kt < 16; ++kt) {
    const int ko = kt * 64;
#pragma unroll
    for (int q = 0; q < 4; ++q) GLL16(aps[q] + ko, ald[q]);
#pragma unroll
    for (int q = 0; q < 4; ++q) GLL16(bps[q] + ko, bld[q]);
    __syncthreads();
#pragma unroll
    for (int ks = 0; ks < 2; ++ks) {
      const int kb = ks * 64 + lg * 16;
      bf16x8 af[4];
#pragma unroll
      for (int mi = 0; mi < 4; ++mi)
        af[mi] = *(const bf16x8*)lds_swz(As, wm + mi * 16 + l15, kb);
#pragma unroll
      for (int ni = 0; ni < 4; ++ni) {
        bf16x8 bfb = *(const bf16x8*)lds_swz(Bs, wn + ni * 16 + l15, kb);
#pragma unroll
        for (int mi = 0; mi < 4; ++mi)
          acc[mi][ni] = __builtin_amdgcn_mfma_f32_16x16x32_bf16(af[mi], bfb, acc[mi][ni], 0, 0, 0);
      }
    }
    __syncthreads();
  }

#pragma unroll
  for (int mi = 0; mi < 4; ++mi) {
    const int rb = wm + mi * 16 + lg * 4;
#pragma unroll
    for (int ni = 0; ni < 4; ++ni) {
      const int col = n0 + wn + ni * 16 + l15;
      f32x4 c = acc[mi][ni];
#pragma unroll
      for (int j = 0; j < 4; ++j) {
        int rr = rb + j;
        int id = rowid[rr];
        if (id >= 0)
          unsafeAtomicAdd(&out[(size_t)(id >> 1) * 1024 + col], c[j] * rw[rr]);
      }
    }
  }
}

extern "C" void kernel_launch(void* const* d_in, const int* in_sizes, int n_in,
                              void* d_out, int out_size, void* d_ws, size_t ws_size,
                              hipStream_t stream)
{
  (void)in_sizes; (void)n_in; (void)out_size; (void)ws_size;
  const float* x  = (const float*)d_in[0];
  const float* gw = (const float*)d_in[1];
  const float* w1 = (const float*)d_in[2];
  const float* w3 = (const float*)d_in[3];
  const float* w2 = (const float*)d_in[4];
  float* out   = (float*)d_out;
  float* probs = out + (size_t)4096 * 1024;

  const size_t MB = (size_t)1 << 20;
  char* ws = (char*)d_ws;
  u16*   xb    = (u16*)(ws);
  u16*   H     = (u16*)(ws + 8 * MB);
  u16*   w1t   = (u16*)(ws + 72 * MB);
  u16*   w3t   = (u16*)(ws + 136 * MB);
  u16*   w2t   = (u16*)(ws + 200 * MB);
  float* wa    = (float*)(ws + 264 * MB);
  int*   alist = (int*)(ws + 264 * MB + 32768);
  int*   cnt   = (int*)(ws + 264 * MB + 32768 + 131072);

  (void)hipMemsetAsync(cnt, 0, 8 * sizeof(int), stream);
  (void)hipMemsetAsync(out, 0, (size_t)4096 * 1024 * sizeof(float), stream);
  rp_k<<<18560, 256, 0, stream>>>(x, gw, probs, xb, wa, alist, cnt, w1, w3, w1t, w3t, w2, w2t);
  gemm1p_k<<<dim3(32, 16, 8), 512, 0, stream>>>(xb, w1t, w3t, alist, cnt, H);
  gemm2_k<<<dim3(8, 128, 8), 256, 0, stream>>>(H, w2t, alist, cnt, wa, out);
}

// Round 17
// 443.595 us; speedup vs baseline: 1.1721x; 1.1031x over previous
//
#include <hip/hip_runtime.h>

typedef unsigned short u16;
typedef unsigned int u32;
typedef __attribute__((ext_vector_type(8))) short bf16x8;
typedef __attribute__((ext_vector_type(4))) float f32x4;
typedef __attribute__((ext_vector_type(4))) int i32x4;
typedef __attribute__((ext_vector_type(2))) unsigned int u32x2;

// T=4096 tokens, D=1024, F=4096, E=8, K=2. Inputs fp32.
// ws: xb(8M) | H(64M) | w1t(64M) | w3t(64M) | w2t(64M) | wa/alist/cnt

__device__ __forceinline__ u16 f2bf(float f) {
  u32 u = __builtin_bit_cast(u32, f);
  u += 0x7fffu + ((u >> 16) & 1u);
  return (u16)(u >> 16);
}
__device__ __forceinline__ u32 pack2(u16 a, u16 b) { return (u32)a | ((u32)b << 16); }
__device__ __forceinline__ u32 cvt2(float a, float b) { return pack2(f2bf(a), f2bf(b)); }

__device__ __forceinline__ char* lds_swz(void* base, int row, int byteInRow) {
  return (char*)base + (((row << 7) + byteInRow) ^ ((row & 7) << 4));
}

#define GLL16(g, l) __builtin_amdgcn_global_load_lds( \
    (const __attribute__((address_space(1))) void*)(g), \
    (__attribute__((address_space(3))) void*)(l), 16, 0, 0)

// ---- 64x64 fp32->bf16 transpose tile helper ----
__device__ __forceinline__ void wtrans_tile2(const float* __restrict__ src, u16* __restrict__ dst,
                                             int R, int C, int c0, int r0, void* lds, int tid)
{
  u16 (*t)[72] = (u16 (*)[72])lds;
  const int rr = (tid >> 4) * 4, cc = (tid & 15) * 4;
  f32x4 v[4];
#pragma unroll
  for (int j = 0; j < 4; ++j) v[j] = *(const f32x4*)(src + (size_t)(r0 + rr + j) * C + c0 + cc);
#pragma unroll
  for (int c = 0; c < 4; ++c) {
    u32x2 p;
    p[0] = pack2(f2bf(v[0][c]), f2bf(v[1][c]));
    p[1] = pack2(f2bf(v[2][c]), f2bf(v[3][c]));
    *(u32x2*)&t[cc + c][rr] = p;
  }
  __syncthreads();
  const int c = tid >> 2, rs = (tid & 3) * 16;
  i32x4 a0 = *(const i32x4*)&t[c][rs];
  i32x4 a1 = *(const i32x4*)&t[c][rs + 8];
  u16* dp = dst + (size_t)(c0 + c) * R + r0 + rs;
  *(i32x4*)dp = a0;
  *(i32x4*)(dp + 8) = a1;
}

// ---------------- launch A: router (blocks 0-127) + w1/w3 transpose ----------------
__global__ __launch_bounds__(256) void rp_k(
    const float* __restrict__ x, const float* __restrict__ gw,
    float* __restrict__ probs, u16* __restrict__ xb,
    float* __restrict__ wa, int* __restrict__ alist, int* __restrict__ cnt,
    const float* __restrict__ w1, const float* __restrict__ w3,
    u16* __restrict__ w1t, u16* __restrict__ w3t)
{
  __shared__ __align__(16) char smem[9216];
  const int bid = blockIdx.x;
  const int tid = threadIdx.x;

  if (bid >= 128) {
    const int b2 = bid - 128;
    const int sel = b2 >> 13;
    const int t0 = b2 & 8191;
    const int e = t0 >> 10;
    const int rem = t0 & 1023;
    const int xt = rem & 63, yt = rem >> 6;
    const float* src = (sel ? w3 : w1) + (size_t)e * 4194304;
    u16* dst = (sel ? w3t : w1t) + (size_t)e * 4194304;
    wtrans_tile2(src, dst, 1024, 4096, xt * 64, yt * 64, smem, tid);
    return;
  }

  int* lcnt  = (int*)smem;
  int* gbase = lcnt + 8;
  int* s_e   = gbase + 8;
  int* s_pos = s_e + 64;
  int* s_row = s_pos + 64;

  const int wv = tid >> 6, l = tid & 63;
  const int tb = bid * 32;

  if (tid < 8) lcnt[tid] = 0;
  __syncthreads();

  for (int i = 0; i < 8; ++i) {
    const int t = tb + wv * 8 + i;
    const float* xrow = x + (size_t)t * 1024;
    f32x4 xv[4];
#pragma unroll
    for (int j = 0; j < 4; ++j) xv[j] = *(const f32x4*)(xrow + j * 256 + l * 4);

    u16* xbt = xb + (size_t)t * 1024;
#pragma unroll
    for (int j = 0; j < 4; ++j) {
      u32x2 hb;
      hb[0] = cvt2(xv[j][0], xv[j][1]);
      hb[1] = cvt2(xv[j][2], xv[j][3]);
      *(u32x2*)(xbt + j * 256 + l * 4) = hb;
    }

    float acc[8];
#pragma unroll
    for (int e = 0; e < 8; ++e) acc[e] = 0.f;
#pragma unroll
    for (int j = 0; j < 4; ++j) {
      const float* g = gw + j * 2048 + l * 32;
#pragma unroll
      for (int c = 0; c < 4; ++c)
#pragma unroll
        for (int e = 0; e < 8; ++e) acc[e] = fmaf(xv[j][c], g[c * 8 + e], acc[e]);
    }
#pragma unroll
    for (int e = 0; e < 8; ++e)
      for (int off = 32; off > 0; off >>= 1) acc[e] += __shfl_down(acc[e], off);

    if (l == 0) {
      float p[8]; float mx = -1e30f;
#pragma unroll
      for (int e = 0; e < 8; ++e) { p[e] = acc[e]; mx = fmaxf(mx, p[e]); }
      float s = 0.f;
#pragma unroll
      for (int e = 0; e < 8; ++e) { p[e] = __expf(p[e] - mx); s += p[e]; }
      float inv = 1.f / s;
#pragma unroll
      for (int e = 0; e < 8; ++e) { p[e] *= inv; probs[(size_t)t * 8 + e] = p[e]; }
      int i0 = 0;
#pragma unroll
      for (int e = 1; e < 8; ++e) if (p[e] > p[i0]) i0 = e;
      int i1 = (i0 == 0) ? 1 : 0;
#pragma unroll
      for (int e = 0; e < 8; ++e) if (e != i0 && p[e] > p[i1]) i1 = e;
      float s2 = p[i0] + p[i1];
      int p0 = atomicAdd(&lcnt[i0], 1);
      int p1 = atomicAdd(&lcnt[i1], 1);
      const int si = (wv * 8 + i) * 2;
      s_e[si] = i0;   s_pos[si] = p0;   s_row[si] = t * 2;
      s_e[si+1] = i1; s_pos[si+1] = p1; s_row[si+1] = t * 2 + 1;
      wa[t * 2]     = p[i0] / s2;
      wa[t * 2 + 1] = p[i1] / s2;
    }
  }
  __syncthreads();
  if (tid < 8) gbase[tid] = atomicAdd(&cnt[tid], lcnt[tid]);
  __syncthreads();
  if (tid < 64) {
    int e = s_e[tid];
    alist[e * 4096 + gbase[e] + s_pos[tid]] = s_row[tid];
  }
}

// ---------------- gemm1 + w2 transpose overlaid (432-build verbatim) ----------------
__global__ __launch_bounds__(256, 2) void gemm1w2_k(
    const u16* __restrict__ xb, const u16* __restrict__ w1t, const u16* __restrict__ w3t,
    const int* __restrict__ alist, const int* __restrict__ cnt, u16* __restrict__ H,
    const float* __restrict__ w2, u16* __restrict__ w2t)
{
  __shared__ __align__(16) char smem[33280];
  const int e = blockIdx.z;
  const int bx = blockIdx.x;

  if (bx >= 64) {
    const float* src = w2 + (size_t)e * 4194304;
    u16* dst = w2t + (size_t)e * 4194304;
    const int slot = (bx - 64) * 32 + blockIdx.y;   // 0..255
#pragma unroll
    for (int j = 0; j < 4; ++j) {
      const int tj = slot * 4 + j;                  // 0..1023
      const int cx = tj & 15, ry = tj >> 4;
      wtrans_tile2(src, dst, 4096, 1024, cx * 64, ry * 64, smem, threadIdx.x);
      __syncthreads();
    }
    return;
  }

  u16* As = (u16*)smem;                  // [128*64]
  u16* Bs = (u16*)(smem + 16384);        // [2][64*64]
  int* rowid = (int*)(smem + 32768);     // [128]

  const int mc = cnt[e];
  const int m0 = blockIdx.y * 128;
  if (m0 >= mc) return;
  const int n0 = bx * 64;
  const int tid = threadIdx.x;

  if (tid < 128) rowid[tid] = (m0 + tid < mc) ? alist[e * 4096 + m0 + tid] : -1;
  __syncthreads();

  const int l = tid & 63, w = tid >> 6;
  const u16* wt = (w >> 1) ? w3t : w1t;
  u16* bbase = Bs + (w >> 1) * 4096;

  const u16* aps[4]; const u16* bps[4];
  u16* ald[4]; u16* bld[4];
#pragma unroll
  for (int q = 0; q < 4; ++q) {
    int ra = 32 * w + 8 * q + (l >> 3);
    int id = rowid[ra];
    aps[q] = xb + (size_t)(id < 0 ? 0 : (id >> 1)) * 1024 + ((l & 7) ^ (ra & 7)) * 8;
    ald[q] = As + (32 * w + 8 * q) * 64;
    int rb = 32 * (w & 1) + 8 * q + (l >> 3);
    bps[q] = wt + (size_t)e * 4194304 + (size_t)(n0 + rb) * 1024 + ((l & 7) ^ (rb & 7)) * 8;
    bld[q] = bbase + (32 * (w & 1) + 8 * q) * 64;
  }

  const int wm = (w >> 1) * 64, wn = (w & 1) * 32;
  const int l15 = l & 15, lg = l >> 4;

  f32x4 acc1[4][2], acc3[4][2];
  const f32x4 zf = {0.f, 0.f, 0.f, 0.f};
#pragma unroll
  for (int mi = 0; mi < 4; ++mi) { acc1[mi][0] = zf; acc1[mi][1] = zf; acc3[mi][0] = zf; acc3[mi][1] = zf; }

  for (int kt = 0; kt < 16; ++kt) {
    const int ko = kt * 64;
#pragma unroll
    for (int q = 0; q < 4; ++q) GLL16(aps[q] + ko, ald[q]);
#pragma unroll
    for (int q = 0; q < 4; ++q) GLL16(bps[q] + ko, bld[q]);
    __syncthreads();
#pragma unroll
    for (int ks = 0; ks < 2; ++ks) {
      const int kb = ks * 64 + lg * 16;
      bf16x8 af[4];
#pragma unroll
      for (int mi = 0; mi < 4; ++mi)
        af[mi] = *(const bf16x8*)lds_swz(As, wm + mi * 16 + l15, kb);
#pragma unroll
      for (int ni = 0; ni < 2; ++ni) {
        bf16x8 b1 = *(const bf16x8*)lds_swz(Bs, wn + ni * 16 + l15, kb);
        bf16x8 b3 = *(const bf16x8*)lds_swz(Bs + 4096, wn + ni * 16 + l15, kb);
#pragma unroll
        for (int mi = 0; mi < 4; ++mi) {
          acc1[mi][ni] = __builtin_amdgcn_mfma_f32_16x16x32_bf16(af[mi], b1, acc1[mi][ni], 0, 0, 0);
          acc3[mi][ni] = __builtin_amdgcn_mfma_f32_16x16x32_bf16(af[mi], b3, acc3[mi][ni], 0, 0, 0);
        }
      }
    }
    __syncthreads();
  }

#pragma unroll
  for (int mi = 0; mi < 4; ++mi) {
    const int rb = wm + mi * 16 + lg * 4;
#pragma unroll
    for (int ni = 0; ni < 2; ++ni) {
      const int col = n0 + wn + ni * 16 + l15;
      f32x4 c1 = acc1[mi][ni], c3 = acc3[mi][ni];
#pragma unroll
      for (int j = 0; j < 4; ++j) {
        int id = rowid[rb + j];
        if (id >= 0) {
          float a = c1[j];
          float h = (a / (1.f + __expf(-a))) * c3[j];
          H[(size_t)id * 4096 + col] = f2bf(h);
        }
      }
    }
  }
}

// ---------------- gemm2 v2: tile 128M x 256N, split-K=4, fused combine ----------------
// wave = 64m x 128n, acc[4][8]; MFMA:ds_read = 64:24 per K-tile (was 32:16).
__global__ __launch_bounds__(256, 2) void gemm2_k(
    const u16* __restrict__ H, const u16* __restrict__ w2t,
    const int* __restrict__ alist, const int* __restrict__ cnt,
    const float* __restrict__ wa, float* __restrict__ out)
{
  const int e = blockIdx.z;
  const int mc = cnt[e];
  const int yy = blockIdx.y;
  const int kq = yy & 3;                 // K quarter: 1024 each
  const int m0 = (yy >> 2) * 128;
  if (m0 >= mc) return;
  const int n0 = blockIdx.x * 256;
  const int tid = threadIdx.x;

  __shared__ u16 As[128 * 64];
  __shared__ u16 Bs[256 * 64];
  __shared__ int rowid[128];
  __shared__ float rw[128];

  if (tid < 128) {
    int id = (m0 + tid < mc) ? alist[e * 4096 + m0 + tid] : -1;
    rowid[tid] = id;
    rw[tid] = (id >= 0) ? wa[id] : 0.f;
  }
  __syncthreads();

  const int l = tid & 63, w = tid >> 6;
  const size_t kbase = (size_t)kq * 1024;
  const u16* aps[4]; u16* ald[4];
  const u16* bps[8]; u16* bld[8];
#pragma unroll
  for (int q = 0; q < 4; ++q) {
    int ra = 32 * w + 8 * q + (l >> 3);
    int id = rowid[ra];
    aps[q] = H + (size_t)(id < 0 ? 0 : id) * 4096 + kbase + ((l & 7) ^ (ra & 7)) * 8;
    ald[q] = As + (32 * w + 8 * q) * 64;
  }
#pragma unroll
  for (int q = 0; q < 8; ++q) {
    int rb = 64 * w + 8 * q + (l >> 3);
    bps[q] = w2t + (size_t)e * 4194304 + (size_t)(n0 + rb) * 4096 + kbase + ((l & 7) ^ (rb & 7)) * 8;
    bld[q] = Bs + (64 * w + 8 * q) * 64;
  }

  const int wm = (w >> 1) * 64, wn = (w & 1) * 128;
  const int l15 = l & 15, lg = l >> 4;

  f32x4 acc[4][8];
  const f32x4 zf = {0.f, 0.f, 0.f, 0.f};
#pragma unroll
  for (int mi = 0; mi < 4; ++mi)
#pragma unroll
    for (int ni = 0; ni < 8; ++ni) acc[mi][ni] = zf;

  for (int kt = 0; kt < 16; ++kt) {
    const int ko = kt * 64;
#pragma unroll
    for (int q = 0; q < 4; ++q) GLL16(aps[q] + ko, ald[q]);
#pragma unroll
    for (int q = 0; q < 8; ++q) GLL16(bps[q] + ko, bld[q]);
    __syncthreads();
#pragma unroll
    for (int ks = 0; ks < 2; ++ks) {
      const int kb = ks * 64 + lg * 16;
      bf16x8 af[4];
#pragma unroll
      for (int mi = 0; mi < 4; ++mi)
        af[mi] = *(const bf16x8*)lds_swz(As, wm + mi * 16 + l15, kb);
#pragma unroll
      for (int ni = 0; ni < 8; ++ni) {
        bf16x8 bfb = *(const bf16x8*)lds_swz(Bs, wn + ni * 16 + l15, kb);
#pragma unroll
        for (int mi = 0; mi < 4; ++mi)
          acc[mi][ni] = __builtin_amdgcn_mfma_f32_16x16x32_bf16(af[mi], bfb, acc[mi][ni], 0, 0, 0);
      }
    }
    __syncthreads();
  }

#pragma unroll
  for (int mi = 0; mi < 4; ++mi) {
    const int rb = wm + mi * 16 + lg * 4;
#pragma unroll
    for (int ni = 0; ni < 8; ++ni) {
      const int col = n0 + wn + ni * 16 + l15;
      f32x4 c = acc[mi][ni];
#pragma unroll
      for (int j = 0; j < 4; ++j) {
        int rr = rb + j;
        int id = rowid[rr];
        if (id >= 0)
          unsafeAtomicAdd(&out[(size_t)(id >> 1) * 1024 + col], c[j] * rw[rr]);
      }
    }
  }
}

extern "C" void kernel_launch(void* const* d_in, const int* in_sizes, int n_in,
                              void* d_out, int out_size, void* d_ws, size_t ws_size,
                              hipStream_t stream)
{
  (void)in_sizes; (void)n_in; (void)out_size; (void)ws_size;
  const float* x  = (const float*)d_in[0];
  const float* gw = (const float*)d_in[1];
  const float* w1 = (const float*)d_in[2];
  const float* w3 = (const float*)d_in[3];
  const float* w2 = (const float*)d_in[4];
  float* out   = (float*)d_out;
  float* probs = out + (size_t)4096 * 1024;

  const size_t MB = (size_t)1 << 20;
  char* ws = (char*)d_ws;
  u16*   xb    = (u16*)(ws);
  u16*   H     = (u16*)(ws + 8 * MB);
  u16*   w1t   = (u16*)(ws + 72 * MB);
  u16*   w3t   = (u16*)(ws + 136 * MB);
  u16*   w2t   = (u16*)(ws + 200 * MB);
  float* wa    = (float*)(ws + 264 * MB);
  int*   alist = (int*)(ws + 264 * MB + 32768);
  int*   cnt   = (int*)(ws + 264 * MB + 32768 + 131072);

  (void)hipMemsetAsync(cnt, 0, 8 * sizeof(int), stream);
  (void)hipMemsetAsync(out, 0, (size_t)4096 * 1024 * sizeof(float), stream);
  rp_k<<<16512, 256, 0, stream>>>(x, gw, probs, xb, wa, alist, cnt, w1, w3, w1t, w3t);
  gemm1w2_k<<<dim3(72, 32, 8), 256, 0, stream>>>(xb, w1t, w3t, alist, cnt, H, w2, w2t);
  gemm2_k<<<dim3(4, 128, 8), 256, 0, stream>>>(H, w2t, alist, cnt, wa, out);
}

// Round 18
// 430.816 us; speedup vs baseline: 1.2069x; 1.0297x over previous
//
#include <hip/hip_runtime.h>

typedef unsigned short u16;
typedef unsigned int u32;
typedef __attribute__((ext_vector_type(8))) short bf16x8;
typedef __attribute__((ext_vector_type(4))) float f32x4;
typedef __attribute__((ext_vector_type(4))) int i32x4;
typedef __attribute__((ext_vector_type(2))) unsigned int u32x2;

// T=4096 tokens, D=1024, F=4096, E=8, K=2. Inputs fp32.
// ws: xb(8M) | H(64M) | w1t(64M) | w3t(64M) | w2t(64M) | wa/alist/cnt

__device__ __forceinline__ u16 f2bf(float f) {
  u32 u = __builtin_bit_cast(u32, f);
  u += 0x7fffu + ((u >> 16) & 1u);
  return (u16)(u >> 16);
}
__device__ __forceinline__ u32 pack2(u16 a, u16 b) { return (u32)a | ((u32)b << 16); }
__device__ __forceinline__ u32 cvt2(float a, float b) { return pack2(f2bf(a), f2bf(b)); }

__device__ __forceinline__ char* lds_swz(void* base, int row, int byteInRow) {
  return (char*)base + (((row << 7) + byteInRow) ^ ((row & 7) << 4));
}

#define GLL16(g, l) __builtin_amdgcn_global_load_lds( \
    (const __attribute__((address_space(1))) void*)(g), \
    (__attribute__((address_space(3))) void*)(l), 16, 0, 0)

// ---- 64x64 fp32->bf16 transpose tile helper ----
__device__ __forceinline__ void wtrans_tile2(const float* __restrict__ src, u16* __restrict__ dst,
                                             int R, int C, int c0, int r0, void* lds, int tid)
{
  u16 (*t)[72] = (u16 (*)[72])lds;
  const int rr = (tid >> 4) * 4, cc = (tid & 15) * 4;
  f32x4 v[4];
#pragma unroll
  for (int j = 0; j < 4; ++j) v[j] = *(const f32x4*)(src + (size_t)(r0 + rr + j) * C + c0 + cc);
#pragma unroll
  for (int c = 0; c < 4; ++c) {
    u32x2 p;
    p[0] = pack2(f2bf(v[0][c]), f2bf(v[1][c]));
    p[1] = pack2(f2bf(v[2][c]), f2bf(v[3][c]));
    *(u32x2*)&t[cc + c][rr] = p;
  }
  __syncthreads();
  const int c = tid >> 2, rs = (tid & 3) * 16;
  i32x4 a0 = *(const i32x4*)&t[c][rs];
  i32x4 a1 = *(const i32x4*)&t[c][rs + 8];
  u16* dp = dst + (size_t)(c0 + c) * R + r0 + rs;
  *(i32x4*)dp = a0;
  *(i32x4*)(dp + 8) = a1;
}

// ---------------- launch A: router (blocks 0-127) + w1/w3 transpose ----------------
__global__ __launch_bounds__(256) void rp_k(
    const float* __restrict__ x, const float* __restrict__ gw,
    float* __restrict__ probs, u16* __restrict__ xb,
    float* __restrict__ wa, int* __restrict__ alist, int* __restrict__ cnt,
    const float* __restrict__ w1, const float* __restrict__ w3,
    u16* __restrict__ w1t, u16* __restrict__ w3t)
{
  __shared__ __align__(16) char smem[9216];
  const int bid = blockIdx.x;
  const int tid = threadIdx.x;

  if (bid >= 128) {
    const int b2 = bid - 128;
    const int sel = b2 >> 13;
    const int t0 = b2 & 8191;
    const int e = t0 >> 10;
    const int rem = t0 & 1023;
    const int xt = rem & 63, yt = rem >> 6;
    const float* src = (sel ? w3 : w1) + (size_t)e * 4194304;
    u16* dst = (sel ? w3t : w1t) + (size_t)e * 4194304;
    wtrans_tile2(src, dst, 1024, 4096, xt * 64, yt * 64, smem, tid);
    return;
  }

  int* lcnt  = (int*)smem;
  int* gbase = lcnt + 8;
  int* s_e   = gbase + 8;
  int* s_pos = s_e + 64;
  int* s_row = s_pos + 64;

  const int wv = tid >> 6, l = tid & 63;
  const int tb = bid * 32;

  if (tid < 8) lcnt[tid] = 0;
  __syncthreads();

  for (int i = 0; i < 8; ++i) {
    const int t = tb + wv * 8 + i;
    const float* xrow = x + (size_t)t * 1024;
    f32x4 xv[4];
#pragma unroll
    for (int j = 0; j < 4; ++j) xv[j] = *(const f32x4*)(xrow + j * 256 + l * 4);

    u16* xbt = xb + (size_t)t * 1024;
#pragma unroll
    for (int j = 0; j < 4; ++j) {
      u32x2 hb;
      hb[0] = cvt2(xv[j][0], xv[j][1]);
      hb[1] = cvt2(xv[j][2], xv[j][3]);
      *(u32x2*)(xbt + j * 256 + l * 4) = hb;
    }

    float acc[8];
#pragma unroll
    for (int e = 0; e < 8; ++e) acc[e] = 0.f;
#pragma unroll
    for (int j = 0; j < 4; ++j) {
      const float* g = gw + j * 2048 + l * 32;
#pragma unroll
      for (int c = 0; c < 4; ++c)
#pragma unroll
        for (int e = 0; e < 8; ++e) acc[e] = fmaf(xv[j][c], g[c * 8 + e], acc[e]);
    }
#pragma unroll
    for (int e = 0; e < 8; ++e)
      for (int off = 32; off > 0; off >>= 1) acc[e] += __shfl_down(acc[e], off);

    if (l == 0) {
      float p[8]; float mx = -1e30f;
#pragma unroll
      for (int e = 0; e < 8; ++e) { p[e] = acc[e]; mx = fmaxf(mx, p[e]); }
      float s = 0.f;
#pragma unroll
      for (int e = 0; e < 8; ++e) { p[e] = __expf(p[e] - mx); s += p[e]; }
      float inv = 1.f / s;
#pragma unroll
      for (int e = 0; e < 8; ++e) { p[e] *= inv; probs[(size_t)t * 8 + e] = p[e]; }
      int i0 = 0;
#pragma unroll
      for (int e = 1; e < 8; ++e) if (p[e] > p[i0]) i0 = e;
      int i1 = (i0 == 0) ? 1 : 0;
#pragma unroll
      for (int e = 0; e < 8; ++e) if (e != i0 && p[e] > p[i1]) i1 = e;
      float s2 = p[i0] + p[i1];
      int p0 = atomicAdd(&lcnt[i0], 1);
      int p1 = atomicAdd(&lcnt[i1], 1);
      const int si = (wv * 8 + i) * 2;
      s_e[si] = i0;   s_pos[si] = p0;   s_row[si] = t * 2;
      s_e[si+1] = i1; s_pos[si+1] = p1; s_row[si+1] = t * 2 + 1;
      wa[t * 2]     = p[i0] / s2;
      wa[t * 2 + 1] = p[i1] / s2;
    }
  }
  __syncthreads();
  if (tid < 8) gbase[tid] = atomicAdd(&cnt[tid], lcnt[tid]);
  __syncthreads();
  if (tid < 64) {
    int e = s_e[tid];
    alist[e * 4096 + gbase[e] + s_pos[tid]] = s_row[tid];
  }
}

// ---------------- gemm1 + w2 transpose overlaid; XCD-banded n-tile remap ----------------
__global__ __launch_bounds__(256, 2) void gemm1w2_k(
    const u16* __restrict__ xb, const u16* __restrict__ w1t, const u16* __restrict__ w3t,
    const int* __restrict__ alist, const int* __restrict__ cnt, u16* __restrict__ H,
    const float* __restrict__ w2, u16* __restrict__ w2t)
{
  __shared__ __align__(16) char smem[33280];
  const int e = blockIdx.z;
  const int bx = blockIdx.x;

  if (bx >= 64) {
    const float* src = w2 + (size_t)e * 4194304;
    u16* dst = w2t + (size_t)e * 4194304;
    const int slot = (bx - 64) * 32 + blockIdx.y;   // 0..255
#pragma unroll
    for (int j = 0; j < 4; ++j) {
      const int tj = slot * 4 + j;                  // 0..1023
      const int cx = tj & 15, ry = tj >> 4;
      wtrans_tile2(src, dst, 4096, 1024, cx * 64, ry * 64, smem, threadIdx.x);
      __syncthreads();
    }
    return;
  }

  u16* As = (u16*)smem;                  // [128*64]
  u16* Bs = (u16*)(smem + 16384);        // [2][64*64]
  int* rowid = (int*)(smem + 32768);     // [128]

  const int mc = cnt[e];
  const int m0 = blockIdx.y * 128;
  if (m0 >= mc) return;
  // XCD-banded n-tile remap: XCD c (= bx%8 for x-fastest dispatch, 72%8==0) gets
  // n-tiles 8c..8c+7 -> its 2 MB of B panels stay L2-resident across all 32 m-tiles.
  const int bxr = (bx & 7) * 8 + (bx >> 3);
  const int n0 = bxr * 64;
  const int tid = threadIdx.x;

  if (tid < 128) rowid[tid] = (m0 + tid < mc) ? alist[e * 4096 + m0 + tid] : -1;
  __syncthreads();

  const int l = tid & 63, w = tid >> 6;
  const u16* wt = (w >> 1) ? w3t : w1t;
  u16* bbase = Bs + (w >> 1) * 4096;

  const u16* aps[4]; const u16* bps[4];
  u16* ald[4]; u16* bld[4];
#pragma unroll
  for (int q = 0; q < 4; ++q) {
    int ra = 32 * w + 8 * q + (l >> 3);
    int id = rowid[ra];
    aps[q] = xb + (size_t)(id < 0 ? 0 : (id >> 1)) * 1024 + ((l & 7) ^ (ra & 7)) * 8;
    ald[q] = As + (32 * w + 8 * q) * 64;
    int rb = 32 * (w & 1) + 8 * q + (l >> 3);
    bps[q] = wt + (size_t)e * 4194304 + (size_t)(n0 + rb) * 1024 + ((l & 7) ^ (rb & 7)) * 8;
    bld[q] = bbase + (32 * (w & 1) + 8 * q) * 64;
  }

  const int wm = (w >> 1) * 64, wn = (w & 1) * 32;
  const int l15 = l & 15, lg = l >> 4;

  f32x4 acc1[4][2], acc3[4][2];
  const f32x4 zf = {0.f, 0.f, 0.f, 0.f};
#pragma unroll
  for (int mi = 0; mi < 4; ++mi) { acc1[mi][0] = zf; acc1[mi][1] = zf; acc3[mi][0] = zf; acc3[mi][1] = zf; }

  for (int kt = 0; kt < 16; ++kt) {
    const int ko = kt * 64;
#pragma unroll
    for (int q = 0; q < 4; ++q) GLL16(aps[q] + ko, ald[q]);
#pragma unroll
    for (int q = 0; q < 4; ++q) GLL16(bps[q] + ko, bld[q]);
    __syncthreads();
#pragma unroll
    for (int ks = 0; ks < 2; ++ks) {
      const int kb = ks * 64 + lg * 16;
      bf16x8 af[4];
#pragma unroll
      for (int mi = 0; mi < 4; ++mi)
        af[mi] = *(const bf16x8*)lds_swz(As, wm + mi * 16 + l15, kb);
#pragma unroll
      for (int ni = 0; ni < 2; ++ni) {
        bf16x8 b1 = *(const bf16x8*)lds_swz(Bs, wn + ni * 16 + l15, kb);
        bf16x8 b3 = *(const bf16x8*)lds_swz(Bs + 4096, wn + ni * 16 + l15, kb);
#pragma unroll
        for (int mi = 0; mi < 4; ++mi) {
          acc1[mi][ni] = __builtin_amdgcn_mfma_f32_16x16x32_bf16(af[mi], b1, acc1[mi][ni], 0, 0, 0);
          acc3[mi][ni] = __builtin_amdgcn_mfma_f32_16x16x32_bf16(af[mi], b3, acc3[mi][ni], 0, 0, 0);
        }
      }
    }
    __syncthreads();
  }

#pragma unroll
  for (int mi = 0; mi < 4; ++mi) {
    const int rb = wm + mi * 16 + lg * 4;
#pragma unroll
    for (int ni = 0; ni < 2; ++ni) {
      const int col = n0 + wn + ni * 16 + l15;
      f32x4 c1 = acc1[mi][ni], c3 = acc3[mi][ni];
#pragma unroll
      for (int j = 0; j < 4; ++j) {
        int id = rowid[rb + j];
        if (id >= 0) {
          float a = c1[j];
          float h = (a / (1.f + __expf(-a))) * c3[j];
          H[(size_t)id * 4096 + col] = f2bf(h);
        }
      }
    }
  }
}

// ---------------- gemm2: out[token] += wa * (H @ w2), split-K=4, fused combine (R14-proven) ----------------
__global__ __launch_bounds__(256, 2) void gemm2_k(
    const u16* __restrict__ H, const u16* __restrict__ w2t,
    const int* __restrict__ alist, const int* __restrict__ cnt,
    const float* __restrict__ wa, float* __restrict__ out)
{
  const int e = blockIdx.z;
  const int mc = cnt[e];
  const int yy = blockIdx.y;
  const int kq = yy & 3;
  const int m0 = (yy >> 2) * 128;
  if (m0 >= mc) return;
  const int n0 = blockIdx.x * 128;
  const int tid = threadIdx.x;

  __shared__ u16 As[128 * 64];
  __shared__ u16 Bs[128 * 64];
  __shared__ int rowid[128];
  __shared__ float rw[128];

  if (tid < 128) {
    int id = (m0 + tid < mc) ? alist[e * 4096 + m0 + tid] : -1;
    rowid[tid] = id;
    rw[tid] = (id >= 0) ? wa[id] : 0.f;
  }
  __syncthreads();

  const int l = tid & 63, w = tid >> 6;
  const size_t kbase = (size_t)kq * 1024;
  const u16* aps[4]; const u16* bps[4];
  u16* ald[4]; u16* bld[4];
#pragma unroll
  for (int q = 0; q < 4; ++q) {
    int ra = 32 * w + 8 * q + (l >> 3);
    int id = rowid[ra];
    aps[q] = H + (size_t)(id < 0 ? 0 : id) * 4096 + kbase + ((l & 7) ^ (ra & 7)) * 8;
    ald[q] = As + (32 * w + 8 * q) * 64;
    int rb = 32 * w + 8 * q + (l >> 3);
    bps[q] = w2t + (size_t)e * 4194304 + (size_t)(n0 + rb) * 4096 + kbase + ((l & 7) ^ (rb & 7)) * 8;
    bld[q] = Bs + (32 * w + 8 * q) * 64;
  }

  const int wm = (w >> 1) * 64, wn = (w & 1) * 64;
  const int l15 = l & 15, lg = l >> 4;

  f32x4 acc[4][4];
  const f32x4 zf = {0.f, 0.f, 0.f, 0.f};
#pragma unroll
  for (int mi = 0; mi < 4; ++mi)
#pragma unroll
    for (int ni = 0; ni < 4; ++ni) acc[mi][ni] = zf;

  for (int kt = 0; kt < 16; ++kt) {
    const int ko = kt * 64;
#pragma unroll
    for (int q = 0; q < 4; ++q) GLL16(aps[q] + ko, ald[q]);
#pragma unroll
    for (int q = 0; q < 4; ++q) GLL16(bps[q] + ko, bld[q]);
    __syncthreads();
#pragma unroll
    for (int ks = 0; ks < 2; ++ks) {
      const int kb = ks * 64 + lg * 16;
      bf16x8 af[4];
#pragma unroll
      for (int mi = 0; mi < 4; ++mi)
        af[mi] = *(const bf16x8*)lds_swz(As, wm + mi * 16 + l15, kb);
#pragma unroll
      for (int ni = 0; ni < 4; ++ni) {
        bf16x8 bfb = *(const bf16x8*)lds_swz(Bs, wn + ni * 16 + l15, kb);
#pragma unroll
        for (int mi = 0; mi < 4; ++mi)
          acc[mi][ni] = __builtin_amdgcn_mfma_f32_16x16x32_bf16(af[mi], bfb, acc[mi][ni], 0, 0, 0);
      }
    }
    __syncthreads();
  }

#pragma unroll
  for (int mi = 0; mi < 4; ++mi) {
    const int rb = wm + mi * 16 + lg * 4;
#pragma unroll
    for (int ni = 0; ni < 4; ++ni) {
      const int col = n0 + wn + ni * 16 + l15;
      f32x4 c = acc[mi][ni];
#pragma unroll
      for (int j = 0; j < 4; ++j) {
        int rr = rb + j;
        int id = rowid[rr];
        if (id >= 0)
          unsafeAtomicAdd(&out[(size_t)(id >> 1) * 1024 + col], c[j] * rw[rr]);
      }
    }
  }
}

extern "C" void kernel_launch(void* const* d_in, const int* in_sizes, int n_in,
                              void* d_out, int out_size, void* d_ws, size_t ws_size,
                              hipStream_t stream)
{
  (void)in_sizes; (void)n_in; (void)out_size; (void)ws_size;
  const float* x  = (const float*)d_in[0];
  const float* gw = (const float*)d_in[1];
  const float* w1 = (const float*)d_in[2];
  const float* w3 = (const float*)d_in[3];
  const float* w2 = (const float*)d_in[4];
  float* out   = (float*)d_out;
  float* probs = out + (size_t)4096 * 1024;

  const size_t MB = (size_t)1 << 20;
  char* ws = (char*)d_ws;
  u16*   xb    = (u16*)(ws);
  u16*   H     = (u16*)(ws + 8 * MB);
  u16*   w1t   = (u16*)(ws + 72 * MB);
  u16*   w3t   = (u16*)(ws + 136 * MB);
  u16*   w2t   = (u16*)(ws + 200 * MB);
  float* wa    = (float*)(ws + 264 * MB);
  int*   alist = (int*)(ws + 264 * MB + 32768);
  int*   cnt   = (int*)(ws + 264 * MB + 32768 + 131072);

  (void)hipMemsetAsync(cnt, 0, 8 * sizeof(int), stream);
  (void)hipMemsetAsync(out, 0, (size_t)4096 * 1024 * sizeof(float), stream);
  rp_k<<<16512, 256, 0, stream>>>(x, gw, probs, xb, wa, alist, cnt, w1, w3, w1t, w3t);
  gemm1w2_k<<<dim3(72, 32, 8), 256, 0, stream>>>(xb, w1t, w3t, alist, cnt, H, w2, w2t);
  gemm2_k<<<dim3(8, 128, 8), 256, 0, stream>>>(H, w2t, alist, cnt, wa, out);
}